// Round 4
// baseline (254.684 us; speedup 1.0000x reference)
//
#include <hip/hip_runtime.h>
#include <hip/hip_bf16.h>

// Problem constants
#define BQ   512   // batch
#define SEQ  128   // L
#define IND  256   // INPUT_DIM
#define POSD 32
#define EMB  512
#define NH   4
#define HDIM 128
#define WID  512
#define OUTD 256

// ---------------------------------------------------------------------------
// Chunked split-K GEMM. Each blockIdx.z computes one K=128 chunk:
//   P[z] = A_z[:, 0:128] @ B_z[0:128, :]     (64x64 tile, 256 thr, 4x4/thr)
// Chunk pointers/ld's come from a by-value descriptor (kernarg, stable for
// graph capture). Partials are summed by reduce kernels (bias/ReLU there).
// ---------------------------------------------------------------------------
struct ChunkDesc {
    const float* A[12];
    const float* B[12];
    int lda[12];
    int ldb[12];
};

__global__ __launch_bounds__(256)
void gemm_chunks_k(ChunkDesc cd, float* __restrict__ P, int ldc, long pStep)
{
    const int BK = 16;
    __shared__ float As[BK][64 + 4];
    __shared__ float Bs[BK][64 + 4];

    const int z = blockIdx.z;
    const float* __restrict__ A = cd.A[z];
    const float* __restrict__ B = cd.B[z];
    const int lda = cd.lda[z];
    const int ldb = cd.ldb[z];
    P += (long)z * pStep;

    const int tid = threadIdx.x;
    const int tx  = tid & 15;      // k-col for A loads, n-group for compute
    const int ty  = tid >> 4;      // m-group
    const int bn  = tid & 63;      // for B loads
    const int bk  = tid >> 6;
    const int m0  = blockIdx.y * 64;
    const int n0  = blockIdx.x * 64;

    float acc[4][4] = {{0.f}};

    for (int k0 = 0; k0 < 128; k0 += BK) {
        #pragma unroll
        for (int i = 0; i < 4; i++)
            As[tx][ty + i * 16] = A[(long)(m0 + ty + i * 16) * lda + (k0 + tx)];
        #pragma unroll
        for (int i = 0; i < 4; i++)
            Bs[bk + i * 4][bn] = B[(long)(k0 + bk + i * 4) * ldb + (n0 + bn)];
        __syncthreads();
        #pragma unroll
        for (int kk = 0; kk < BK; kk++) {
            float a4[4], b4[4];
            *(float4*)a4 = *(const float4*)&As[kk][ty * 4];
            *(float4*)b4 = *(const float4*)&Bs[kk][tx * 4];
            #pragma unroll
            for (int i = 0; i < 4; i++)
                #pragma unroll
                for (int j = 0; j < 4; j++)
                    acc[i][j] = fmaf(a4[i], b4[j], acc[i][j]);
        }
        __syncthreads();
    }

    const int gn = n0 + tx * 4;
    #pragma unroll
    for (int i = 0; i < 4; i++) {
        const int gm = m0 + ty * 4 + i;
        float4 v;
        v.x = acc[i][0]; v.y = acc[i][1]; v.z = acc[i][2]; v.w = acc[i][3];
        *(float4*)&P[(long)gm * ldc + gn] = v;
    }
}

// ---------------------------------------------------------------------------
// Generic partial reduce: C[e] = act( sum_s P[s][e] + bias[col] if row>=start )
// One float4 per thread; total elements = gridDim.x * 1024 (exact).
// ---------------------------------------------------------------------------
template<bool RELU>
__global__ __launch_bounds__(256)
void reduce_k(const float* __restrict__ P, long pStep, int nsl,
              const float* __restrict__ bias, int biasStartRow, int ldn,
              float* __restrict__ C)
{
    const long e = ((long)blockIdx.x * 256 + threadIdx.x) * 4;
    float4 s = *(const float4*)(P + e);
    for (int i = 1; i < nsl; i++) {
        const float4 p = *(const float4*)(P + (long)i * pStep + e);
        s.x += p.x; s.y += p.y; s.z += p.z; s.w += p.w;
    }
    if (bias) {
        const int row = (int)(e / ldn);
        if (row >= biasStartRow) {
            const int col = (int)(e % ldn);
            const float4 bv = *(const float4*)(bias + col);
            s.x += bv.x; s.y += bv.y; s.z += bv.z; s.w += bv.w;
        }
    }
    if (RELU) {
        s.x = fmaxf(s.x, 0.f); s.y = fmaxf(s.y, 0.f);
        s.z = fmaxf(s.z, 0.f); s.w = fmaxf(s.w, 0.f);
    }
    *(float4*)(C + e) = s;
}

// ---------------------------------------------------------------------------
// Fused Wf+PQ GEMM with split-K (ks = blockIdx.z, K chunk 128):
//   combined rows 0..255 : Wf = W_embed[0:256] @ W_attn
//   combined rows 256..383: PQ = PB @ W_attn     (bias added in reduce)
// Partial P[ks][384][1536].
// ---------------------------------------------------------------------------
__global__ __launch_bounds__(256)
void wfpq_sk_k(const float* __restrict__ W_embed, const float* __restrict__ PB,
               const float* __restrict__ W_attn, float* __restrict__ P)
{
    const int BK = 16;
    __shared__ float As[BK][64 + 4];
    __shared__ float Bs[BK][64 + 4];

    const int tid = threadIdx.x;
    const int tx  = tid & 15;
    const int ty  = tid >> 4;
    const int bn  = tid & 63;
    const int bk  = tid >> 6;
    const int ks  = blockIdx.z;          // 0..3, K chunk base = ks*128
    const int kb  = ks * 128;
    const int m0c = blockIdx.y * 64;     // combined row 0..383
    const bool top = m0c < 256;
    const int n0  = blockIdx.x * 64;
    const float* A = top ? (W_embed + (long)m0c * 512)
                         : (PB + (long)(m0c - 256) * 512);   // lda=512 both
    P += (long)ks * (384 * 1536);

    float acc[4][4] = {{0.f}};

    for (int k0 = 0; k0 < 128; k0 += BK) {
        #pragma unroll
        for (int i = 0; i < 4; i++)
            As[tx][ty + i * 16] = A[(long)(ty + i * 16) * 512 + (kb + k0 + tx)];
        #pragma unroll
        for (int i = 0; i < 4; i++)
            Bs[bk + i * 4][bn] = W_attn[(long)(kb + k0 + bk + i * 4) * 1536 + (n0 + bn)];
        __syncthreads();
        #pragma unroll
        for (int kk = 0; kk < BK; kk++) {
            float a4[4], b4[4];
            *(float4*)a4 = *(const float4*)&As[kk][ty * 4];
            *(float4*)b4 = *(const float4*)&Bs[kk][tx * 4];
            #pragma unroll
            for (int i = 0; i < 4; i++)
                #pragma unroll
                for (int j = 0; j < 4; j++)
                    acc[i][j] = fmaf(a4[i], b4[j], acc[i][j]);
        }
        __syncthreads();
    }

    const int gn = n0 + tx * 4;
    #pragma unroll
    for (int i = 0; i < 4; i++) {
        const int gm = m0c + ty * 4 + i;
        float4 v;
        v.x = acc[i][0]; v.y = acc[i][1]; v.z = acc[i][2]; v.w = acc[i][3];
        *(float4*)&P[(long)gm * 1536 + gn] = v;
    }
}

// ---------------------------------------------------------------------------
// ctx reduce: CTX[m, h*128+n] = sum_{ks<3} P[h*3+ks][m][n]
// grid (64, 4): x covers 512*128/1024 elems, y = head.
// ---------------------------------------------------------------------------
__global__ __launch_bounds__(256)
void ctx_reduce_k(const float* __restrict__ P, float* __restrict__ CTX)
{
    const int h = blockIdx.y;
    const long e = ((long)blockIdx.x * 256 + threadIdx.x) * 4;  // within [0,65536)
    const long base = (long)h * 3 * 65536;
    float4 s = *(const float4*)(P + base + e);
    #pragma unroll
    for (int i = 1; i < 3; i++) {
        const float4 p = *(const float4*)(P + base + (long)i * 65536 + e);
        s.x += p.x; s.y += p.y; s.z += p.z; s.w += p.w;
    }
    const int m = (int)(e >> 7);
    const int n = (int)(e & 127);
    *(float4*)&CTX[(long)m * EMB + h * HDIM + n] = s;
}

// ---------------------------------------------------------------------------
// Fused: sinusoid rel-pos -> r = flip(enc) @ W_r -> PB = r @ W_embed[256:] + b_embed
// f32 throughout to track JAX rounding.
// ---------------------------------------------------------------------------
__global__ __launch_bounds__(256)
void pos_pb_k(const float* __restrict__ W_r, const float* __restrict__ W_embed,
              const float* __restrict__ b_embed, float* __restrict__ PB)
{
    __shared__ float r[POSD];
    const int p   = blockIdx.x;        // 0..127
    const int tid = threadIdx.x;

    if (tid < POSD) {
        const int pos = (SEQ - 1) - p;  // flip axis 0
        float acc = 0.f;
        #pragma unroll
        for (int i = 0; i < POSD; i++) {
            float expo  = powf(10000.0f, (2.0f * i) / (float)POSD);
            float angle = (float)pos / expo;
            float Ri    = ((i & 1) == 0) ? sinf(angle) : cosf(angle);
            acc = fmaf(Ri, W_r[i * POSD + tid], acc);
        }
        r[tid] = acc;
    }
    __syncthreads();

    for (int c = tid; c < EMB; c += 256) {
        float acc = b_embed[c];
        #pragma unroll
        for (int i = 0; i < POSD; i++)
            acc = fmaf(r[i], W_embed[(IND + i) * EMB + c], acc);
        PB[p * EMB + c] = acc;
    }
}

// ---------------------------------------------------------------------------
// Fused steps "T" + "SP": per-head (z=h) GEMM  C = Q_h @ B^T, K=128.
//   blockIdx.x < 4 : B rows = Wf[:,512+h*128] cols as K   -> T  (ldc 256)
//   blockIdx.x >= 4: B rows = PQ[:,512+h*128]             -> SP (ldc 128)
// ---------------------------------------------------------------------------
__global__ __launch_bounds__(256)
void tsp_k(const float* __restrict__ Q, const float* __restrict__ Wf,
           const float* __restrict__ PQ,
           float* __restrict__ T, float* __restrict__ SP)
{
    const int BK = 16;
    __shared__ float As[BK][64 + 4];
    __shared__ float Bs[BK][64 + 4];

    const int h   = blockIdx.z;
    const int tid = threadIdx.x;
    const int tx  = tid & 15;
    const int ty  = tid >> 4;
    const bool isT = blockIdx.x < 4;
    const int n0  = (isT ? blockIdx.x : blockIdx.x - 4) * 64;
    const int m0  = blockIdx.y * 64;

    const float* A = Q + h * HDIM;                        // lda 512
    const float* B = (isT ? Wf : PQ) + 512 + h * HDIM;    // ldb 1536, [n*1536+k]
    float* C       = isT ? (T + (long)h * BQ * IND) : (SP + (long)h * BQ * SEQ);
    const int ldc  = isT ? IND : SEQ;

    float acc[4][4] = {{0.f}};

    for (int k0 = 0; k0 < HDIM; k0 += BK) {
        #pragma unroll
        for (int i = 0; i < 4; i++)
            As[tx][ty + i * 16] = A[(long)(m0 + ty + i * 16) * 512 + (k0 + tx)];
        #pragma unroll
        for (int i = 0; i < 4; i++)
            Bs[tx][ty + i * 16] = B[(long)(n0 + ty + i * 16) * 1536 + (k0 + tx)];
        __syncthreads();
        #pragma unroll
        for (int kk = 0; kk < BK; kk++) {
            float a4[4], b4[4];
            *(float4*)a4 = *(const float4*)&As[kk][ty * 4];
            *(float4*)b4 = *(const float4*)&Bs[kk][tx * 4];
            #pragma unroll
            for (int i = 0; i < 4; i++)
                #pragma unroll
                for (int j = 0; j < 4; j++)
                    acc[i][j] = fmaf(a4[i], b4[j], acc[i][j]);
        }
        __syncthreads();
    }

    const int gn = n0 + tx * 4;
    #pragma unroll
    for (int i = 0; i < 4; i++) {
        const int gm = m0 + ty * 4 + i;
        float4 v;
        v.x = acc[i][0]; v.y = acc[i][1]; v.z = acc[i][2]; v.w = acc[i][3];
        *(float4*)&C[(long)gm * ldc + gn] = v;
    }
}

// ---------------------------------------------------------------------------
// Per-batch attention for the last query row only.
//   scores[h,k] = ( sum_j x[k,j]*t[h,j] + SP[h,k] ) / sqrt(128)
//   attn = softmax_k(scores);  U[h,j] = sum_k attn[h,k]*x[k,j]
// x[b] (128x256 f32, padded) staged in LDS.
// ---------------------------------------------------------------------------
__global__ __launch_bounds__(512)
void attn_k(const float* __restrict__ hist,
            const float* __restrict__ T,    // [4][512][256]
            const float* __restrict__ SP,   // [4][512][128]
            float* __restrict__ ATN,        // [4][512][128]
            float* __restrict__ U)          // [4][512][256]
{
    const int b   = blockIdx.x;
    const int tid = threadIdx.x;

    __shared__ float x[SEQ][IND + 1];   // +1 pad: conflict-free column access
    __shared__ float t[NH][IND];
    __shared__ float sc[NH][SEQ];
    __shared__ float tmp[NH][SEQ];

    // stage x[b] : 8192 float4
    const float4* src = (const float4*)(hist + (long)b * SEQ * IND);
    #pragma unroll
    for (int i = 0; i < 16; i++) {
        int idx = tid + i * 512;
        int k   = idx >> 6;
        int j4  = (idx & 63) << 2;
        float4 v = src[idx];
        x[k][j4 + 0] = v.x; x[k][j4 + 1] = v.y;
        x[k][j4 + 2] = v.z; x[k][j4 + 3] = v.w;
    }
    // stage t : 1024 floats
    #pragma unroll
    for (int i = 0; i < 2; i++) {
        int idx = tid + i * 512;
        int h = idx >> 8, j = idx & 255;
        t[h][j] = T[(long)h * (BQ * IND) + (long)b * IND + j];
    }
    // stage SP into sc
    {
        int h = tid >> 7, k = tid & 127;
        sc[h][k] = SP[(long)h * (BQ * SEQ) + b * SEQ + k];
    }
    __syncthreads();

    // ---- scores ----
    const int h = tid >> 7;      // 0..3
    const int k = tid & 127;     // 0..127
    const float* xr = &x[k][0];
    const float* tr = &t[h][0];
    float sraw = 0.f;
    #pragma unroll 8
    for (int j = 0; j < IND; j++)
        sraw = fmaf(xr[j], tr[j], sraw);
    const float s = (sraw + sc[h][k]) * 0.08838834764831845f;  // 1/sqrt(128)

    // ---- softmax over k per h ----
    tmp[h][k] = s;
    __syncthreads();
    for (int st = 64; st > 0; st >>= 1) {
        if (k < st) tmp[h][k] = fmaxf(tmp[h][k], tmp[h][k + st]);
        __syncthreads();
    }
    const float mx_ = tmp[h][0];
    __syncthreads();
    const float e = expf(s - mx_);
    tmp[h][k] = e;
    __syncthreads();
    for (int st = 64; st > 0; st >>= 1) {
        if (k < st) tmp[h][k] += tmp[h][k + st];
        __syncthreads();
    }
    const float a = e / tmp[h][0];
    sc[h][k] = a;
    ATN[(long)h * (BQ * SEQ) + b * SEQ + k] = a;
    __syncthreads();

    // ---- U[h,j] = sum_k attn[h,k] * x[k,j] ; each thread does h and h+2 ----
    const int j  = tid & 255;
    const int hh = tid >> 8;     // 0 or 1
    const float* a0 = &sc[hh][0];
    const float* a1 = &sc[hh + 2][0];
    float u0 = 0.f, u1 = 0.f;
    #pragma unroll 4
    for (int kk = 0; kk < SEQ; kk++) {
        float xv = x[kk][j];
        u0 = fmaf(a0[kk], xv, u0);
        u1 = fmaf(a1[kk], xv, u1);
    }
    U[(long)hh       * (BQ * IND) + b * IND + j] = u0;
    U[(long)(hh + 2) * (BQ * IND) + b * IND + j] = u1;
}

// ---------------------------------------------------------------------------
// Final: v = relu( sum_{s<6} P[s][b][c] + b5[c] + b_skip[c] );
//        out = 2*(v - min)/(max - min) - 1   (per row of 256)
// ---------------------------------------------------------------------------
__global__ __launch_bounds__(256)
void final_k(const float* __restrict__ P,   // 6 slices of [512][256]
             const float* __restrict__ b5, const float* __restrict__ b_skip,
             float* __restrict__ out)
{
    const int b = blockIdx.x, tid = threadIdx.x;
    const long e = (long)b * OUTD + tid;
    float v = b5[tid] + b_skip[tid];
    #pragma unroll
    for (int s = 0; s < 6; s++)
        v += P[(long)s * (BQ * OUTD) + e];
    v = fmaxf(v, 0.f);

    __shared__ float mn[4], mx[4];
    float lo = v, hi = v;
    #pragma unroll
    for (int off = 32; off > 0; off >>= 1) {
        lo = fminf(lo, __shfl_down(lo, off));
        hi = fmaxf(hi, __shfl_down(hi, off));
    }
    const int w = tid >> 6;
    if ((tid & 63) == 0) { mn[w] = lo; mx[w] = hi; }
    __syncthreads();
    if (tid == 0) {
        float l0 = mn[0], h0 = mx[0];
        for (int i = 1; i < 4; i++) { l0 = fminf(l0, mn[i]); h0 = fmaxf(h0, mx[i]); }
        mn[0] = l0; mx[0] = h0;
    }
    __syncthreads();
    const float lo0 = mn[0], hi0 = mx[0];
    out[e] = 2.f * (v - lo0) / (hi0 - lo0) - 1.f;
}

// ---------------------------------------------------------------------------
extern "C" void kernel_launch(void* const* d_in, const int* in_sizes, int n_in,
                              void* d_out, int out_size, void* d_ws, size_t ws_size,
                              hipStream_t stream)
{
    const float* hist    = (const float*)d_in[0];
    // d_in[1] end_pos: provably unused — for the last query row (q=L-1),
    // k_idx - q_idx <= 0 < end_pos (end_pos >= 1), so the mask never fires.
    const float* W_embed = (const float*)d_in[2];   // 288 x 512
    const float* b_embed = (const float*)d_in[3];
    const float* W_r     = (const float*)d_in[4];   // 32 x 32
    const float* W_attn  = (const float*)d_in[5];   // 512 x 1536
    const float* b_attn  = (const float*)d_in[6];
    const float* W_proj  = (const float*)d_in[7];   // 512 x 512
    const float* b_proj  = (const float*)d_in[8];
    const float* W_skip  = (const float*)d_in[9];   // 256 x 256
    const float* b_skip  = (const float*)d_in[10];
    const float* W1      = (const float*)d_in[11];  // 512 x 512
    const float* b1      = (const float*)d_in[12];
    const float* W2      = (const float*)d_in[13];  // 512 x 512
    const float* b2      = (const float*)d_in[14];
    const float* W5      = (const float*)d_in[15];  // 512 x 256
    const float* b5      = (const float*)d_in[16];
    float* out = (float*)d_out;
    float* ws  = (float*)d_ws;

    // workspace layout (floats); later buffers alias earlier dead ones
    float* PB   = ws;                 //  65536  pos_bias (128x512)
    float* Wf   = ws + 65536;         // 393216  W_embed[0:256] @ W_attn (256x1536)
    float* PQ   = ws + 458752;        // 196608  PB @ W_attn + b_attn (128x1536)  [contig after Wf]
    float* Q    = ws + 655360;        // 262144  last-row q (512x512)
    float* T    = ws + 917504;        // 524288  t = Wek·q   [4][512][256]
    float* SP   = ws + 1441792;       // 262144  q·pos_k     [4][512][128]
    float* ATN  = ws + 1703936;       // 262144  attn        [4][512][128]
    float* U    = ws + 1966080;       // 524288  attn·x      [4][512][256]
    float* CTX  = ws + 2490368;       // 262144  (512x512)
    float* PART = ws + 2752512;       // up to 2359296 (wfpq partials 4x384x1536)
    float* O1   = ws + 655360;        // reuse Q   (dead after tsp)
    float* X1   = ws + 917504;        // reuse T   (dead after attn)
    float* X2   = ws + 1441792;       // reuse SP  (dead after attn)
    (void)ws_size; (void)in_sizes; (void)n_in; (void)out_size;

    // 1) positional basis + pos_bias (fused)
    pos_pb_k<<<SEQ, 256, 0, stream>>>(W_r, W_embed, b_embed, PB);

    // 2) Wf (rows 0..255) + PQ (rows 256..383), split-K x4 -> partials
    wfpq_sk_k<<<dim3(24, 6, 4), 256, 0, stream>>>(W_embed, PB, W_attn, PART);
    // 3) reduce: Wf|PQ contiguous 384x1536; bias b_attn only for rows >= 256
    reduce_k<false><<<576, 256, 0, stream>>>(PART, 384L * 1536, 4,
                                             b_attn, 256, 1536, Wf);

    // 4) Q = hist[:,127,:] @ Wf[:, :512] (+ PQ[127,:512] in reduce), split-K x2
    {
        ChunkDesc cd{};
        cd.A[0] = hist + 127 * IND;        cd.lda[0] = SEQ * IND;
        cd.B[0] = Wf;                      cd.ldb[0] = 1536;
        cd.A[1] = hist + 127 * IND + 128;  cd.lda[1] = SEQ * IND;
        cd.B[1] = Wf + 128L * 1536;        cd.ldb[1] = 1536;
        gemm_chunks_k<<<dim3(8, 8, 2), 256, 0, stream>>>(cd, PART, 512, 512L * 512);
    }
    reduce_k<false><<<256, 256, 0, stream>>>(PART, 512L * 512, 2,
                                             PQ + 127L * 1536, 0, 512, Q);

    // 5) T_h = Q_h @ Wek_h^T  and  SP_h = Q_h @ pos_k_h^T  (fused, z=4)
    tsp_k<<<dim3(6, 8, 4), 256, 0, stream>>>(Q, Wf, PQ, T, SP);

    // 6) attention (one block per batch)
    attn_k<<<BQ, 512, 0, stream>>>(hist, T, SP, ATN, U);

    // 7) CTX_h = ATN_h @ pos_v_h + U_h @ Wev_h, 3 chunks per head (z=12)
    {
        ChunkDesc cd{};
        for (int h = 0; h < NH; h++) {
            cd.A[h * 3 + 0] = ATN + (long)h * BQ * SEQ;        cd.lda[h * 3 + 0] = SEQ;
            cd.B[h * 3 + 0] = PQ + 1024 + h * HDIM;            cd.ldb[h * 3 + 0] = 1536;
            cd.A[h * 3 + 1] = U + (long)h * BQ * IND;          cd.lda[h * 3 + 1] = IND;
            cd.B[h * 3 + 1] = Wf + 1024 + h * HDIM;            cd.ldb[h * 3 + 1] = 1536;
            cd.A[h * 3 + 2] = U + (long)h * BQ * IND + 128;    cd.lda[h * 3 + 2] = IND;
            cd.B[h * 3 + 2] = Wf + 1024 + h * HDIM + 128L * 1536; cd.ldb[h * 3 + 2] = 1536;
        }
        gemm_chunks_k<<<dim3(2, 8, 12), 256, 0, stream>>>(cd, PART, 128, 512L * 128);
    }
    // 8) reduce partials into head-interleaved CTX
    ctx_reduce_k<<<dim3(64, 4), 256, 0, stream>>>(PART, CTX);

    // 9) out_last = CTX @ W_proj (+ b_proj in reduce), split-K x4
    {
        ChunkDesc cd{};
        for (int i = 0; i < 4; i++) {
            cd.A[i] = CTX + i * 128;              cd.lda[i] = 512;
            cd.B[i] = W_proj + (long)i * 128 * 512; cd.ldb[i] = 512;
        }
        gemm_chunks_k<<<dim3(8, 8, 4), 256, 0, stream>>>(cd, PART, 512, 512L * 512);
    }
    reduce_k<false><<<256, 256, 0, stream>>>(PART, 512L * 512, 4, b_proj, 0, 512, O1);

    // 10) X1 = relu(O1 @ W1 + b1), split-K x4
    {
        ChunkDesc cd{};
        for (int i = 0; i < 4; i++) {
            cd.A[i] = O1 + i * 128;               cd.lda[i] = 512;
            cd.B[i] = W1 + (long)i * 128 * 512;   cd.ldb[i] = 512;
        }
        gemm_chunks_k<<<dim3(8, 8, 4), 256, 0, stream>>>(cd, PART, 512, 512L * 512);
    }
    reduce_k<true><<<256, 256, 0, stream>>>(PART, 512L * 512, 4, b1, 0, 512, X1);

    // 11) X2 = relu(X1 @ W2 + b2), split-K x4
    {
        ChunkDesc cd{};
        for (int i = 0; i < 4; i++) {
            cd.A[i] = X1 + i * 128;               cd.lda[i] = 512;
            cd.B[i] = W2 + (long)i * 128 * 512;   cd.ldb[i] = 512;
        }
        gemm_chunks_k<<<dim3(8, 8, 4), 256, 0, stream>>>(cd, PART, 512, 512L * 512);
    }
    reduce_k<true><<<256, 256, 0, stream>>>(PART, 512L * 512, 4, b2, 0, 512, X2);

    // 12) XP partials = X2 @ W5 (4 chunks) + hist[:,0,:] @ W_skip (2 chunks)
    {
        ChunkDesc cd{};
        for (int i = 0; i < 4; i++) {
            cd.A[i] = X2 + i * 128;               cd.lda[i] = 512;
            cd.B[i] = W5 + (long)i * 128 * 256;   cd.ldb[i] = 256;
        }
        cd.A[4] = hist;        cd.lda[4] = SEQ * IND;
        cd.B[4] = W_skip;      cd.ldb[4] = 256;
        cd.A[5] = hist + 128;  cd.lda[5] = SEQ * IND;
        cd.B[5] = W_skip + 128L * 256; cd.ldb[5] = 256;
        gemm_chunks_k<<<dim3(4, 8, 6), 256, 0, stream>>>(cd, PART, 256, 512L * 256);
    }
    // 13) final: sum 6 partials + b5 + b_skip, relu, min/max normalize
    final_k<<<BQ, 256, 0, stream>>>(PART, b5, b_skip, out);
}